// Round 6
// baseline (302.879 us; speedup 1.0000x reference)
//
#include <hip/hip_runtime.h>
#include <math.h>

// GraphSAGE 2-layer, mean aggregation, fp32.
// Round 6: R3/R5 both failed with wave-level shfl-broadcast l1 variants;
// R2/R4 block-level variants passed. Conclusion: avoid the unverifiable
// pattern entirely. This round splits R4's latency-bound fused l1
// (169us, VALUBusy 23%: barriers lock-step 4 waves onto serial gather
// chains) into two simple, separately-verifiable kernels:
//   (a) gather_mean: 32 lanes/node, each lane owns one of 19 channels and
//       privately sums over neighbors. No shuffles, no barriers, no
//       cross-lane anything. 3.2M threads of TLP. Writes mean1 [N][19].
//   (b) dense: R4's matmul + layer-2 projection VERBATIM, gather replaced
//       by a mean1 read. Regular, barrier-cheap, compute-bound.
// CSR build / final_kernel: R4 verbatim (passing).

constexpr int N    = 100000;
constexpr int E    = 1600000;
constexpr int INC  = 19;
constexpr int HID  = 128;
constexpr int OUTC = 4;
constexpr int NB   = (N + 255) / 256;   // 391 scan blocks

// ---- kernel 0: detect whether edge_index arrived as int64 or int32 -------
__global__ void detect_idx64(const int* __restrict__ ei, int* __restrict__ flag) {
    __shared__ int any;
    if (threadIdx.x == 0) any = 0;
    __syncthreads();
    int v = 0;
    for (int k = threadIdx.x; k < 1024; k += blockDim.x)
        v |= ei[2 * k + 1];
    if (v) atomicOr(&any, 1);
    __syncthreads();
    if (threadIdx.x == 0) *flag = (any == 0) ? 1 : 0;
}

__device__ inline void load_edge(const int* __restrict__ ei, int e, int is64,
                                 int& src, int& dst) {
    if (is64) {
        src = ei[2 * e];
        dst = ei[2 * E + 2 * e];
    } else {
        src = ei[e];
        dst = ei[E + e];
    }
}

// ---- kernel 1: degree histogram + per-edge rank ---------------------------
__global__ void deg_rank_kernel(const int* __restrict__ ei, int* __restrict__ deg,
                                int* __restrict__ rank, const int* __restrict__ flag) {
    int e = blockIdx.x * blockDim.x + threadIdx.x;
    if (e >= E) return;
    int is64 = *flag;
    int dst = is64 ? ei[2 * E + 2 * e] : ei[E + e];
    rank[e] = atomicAdd(&deg[dst], 1);
}

// ---- kernels 2a/2b/2c: exclusive scan of deg -> start ----------------------
__global__ void scan_block(const int* __restrict__ deg, int* __restrict__ start,
                           int* __restrict__ bsum) {
    __shared__ int sd[256];
    int t = threadIdx.x;
    int i = blockIdx.x * 256 + t;
    int v = (i < N) ? deg[i] : 0;
    sd[t] = v;
    __syncthreads();
    for (int off = 1; off < 256; off <<= 1) {
        int add = (t >= off) ? sd[t - off] : 0;
        __syncthreads();
        sd[t] += add;
        __syncthreads();
    }
    if (i < N) start[i] = sd[t] - v;
    if (t == 255) bsum[blockIdx.x] = sd[255];
}

__global__ void scan_bsum(int* __restrict__ bsum) {
    __shared__ int sd[512];
    int t = threadIdx.x;
    int v = (t < NB) ? bsum[t] : 0;
    sd[t] = v;
    __syncthreads();
    for (int off = 1; off < 512; off <<= 1) {
        int add = (t >= off) ? sd[t - off] : 0;
        __syncthreads();
        sd[t] += add;
        __syncthreads();
    }
    if (t < NB) bsum[t] = sd[t] - v;
}

__global__ void scan_addback(int* __restrict__ start, const int* __restrict__ bsum) {
    int i = blockIdx.x * 256 + threadIdx.x;
    if (i < N) start[i] += bsum[blockIdx.x];
}

// ---- kernel 3: atomic-free scatter into CSR -------------------------------
__global__ void scatter_kernel(const int* __restrict__ ei, const int* __restrict__ start,
                               const int* __restrict__ rank, int* __restrict__ adj,
                               const int* __restrict__ flag) {
    int e = blockIdx.x * blockDim.x + threadIdx.x;
    if (e >= E) return;
    int is64 = *flag;
    int src, dst;
    load_edge(ei, e, is64, src, dst);
    adj[start[dst] + rank[e]] = src;
}

// ---- kernel 4a: gather-mean, 32 lanes per node, one channel per lane ------
// No shuffles, no barriers: lane privately sums its channel over neighbors.
__global__ void gather_mean_kernel(const float* __restrict__ x,
                                   const int* __restrict__ adj,
                                   const int* __restrict__ start,
                                   const int* __restrict__ deg,
                                   float* __restrict__ mean1) {
    int tid  = blockIdx.x * blockDim.x + threadIdx.x;
    int node = tid >> 5;
    int ln   = tid & 31;
    if (node >= N || ln >= INC) return;
    int d  = deg[node];
    int st = start[node];
    float a0 = 0.f, a1 = 0.f;
    int j = 0;
    for (; j + 1 < d; j += 2) {
        int s0 = adj[st + j];
        int s1 = adj[st + j + 1];
        a0 += x[(size_t)s0 * INC + ln];
        a1 += x[(size_t)s1 * INC + ln];
    }
    if (j < d) a0 += x[(size_t)adj[st + j] * INC + ln];
    float inv = 1.0f / fmaxf((float)d, 1.0f);
    mean1[(size_t)node * INC + ln] = (a0 + a1) * inv;
}

// ---- kernel 4b: dense layer1 matmul + layer2 projection (R4 verbatim math)
// 256-thread block = 2 nodes per iteration (half-block each), w1 in LDS,
// w2 in registers, grid-stride.
__global__ __launch_bounds__(256) void dense_kernel(
        const float* __restrict__ x,
        const float* __restrict__ mean1,
        const float* __restrict__ w1l,
        const float* __restrict__ w1r,
        const float* __restrict__ b1,
        const float* __restrict__ w2l,
        const float* __restrict__ w2r,
        float* __restrict__ g,
        float* __restrict__ s) {
    __shared__ float W1L[INC * HID];
    __shared__ float W1R[INC * HID];
    __shared__ float xs[2][INC];
    __shared__ float ms[2][INC];
    __shared__ float hs[2][HID];

    int t   = threadIdx.x;     // 0..255
    int sub = t >> 7;          // node slot (half-block)
    int tt  = t & 127;         // thread-in-slot

    for (int k = t; k < INC * HID; k += 256) {
        W1L[k] = w1l[k];
        W1R[k] = w1r[k];
    }
    float bb = b1[tt];
    const float* w2p = (tt < 64) ? w2l : w2r;
    int l = tt & 63;
    float w2reg[8];
#pragma unroll
    for (int k = 0; k < OUTC; ++k) {
        w2reg[k]     = w2p[l * OUTC + k];
        w2reg[4 + k] = w2p[(l + 64) * OUTC + k];
    }
    __syncthreads();

    for (int base = blockIdx.x * 2; base < N; base += gridDim.x * 2) {
        int node = base + sub;

        if (node < N && tt < INC) {
            ms[sub][tt] = mean1[(size_t)node * INC + tt];
            xs[sub][tt] = x[(size_t)node * INC + tt];
        }
        __syncthreads();

        // layer-1 matmul (R4 verbatim, weights from LDS)
        float acc = bb;
#pragma unroll
        for (int c = 0; c < INC; ++c)
            acc += ms[sub][c] * W1L[c * HID + tt] + xs[sub][c] * W1R[c * HID + tt];
        hs[sub][tt] = fmaxf(acc, 0.0f);
        __syncthreads();

        // layer-2 projection (R4 verbatim): columns l and l+64
        float a0, a1, a2, a3;
        {
            float hv = hs[sub][l];
            a0 = hv * w2reg[0]; a1 = hv * w2reg[1];
            a2 = hv * w2reg[2]; a3 = hv * w2reg[3];
            hv = hs[sub][l + 64];
            a0 += hv * w2reg[4]; a1 += hv * w2reg[5];
            a2 += hv * w2reg[6]; a3 += hv * w2reg[7];
        }
#pragma unroll
        for (int o = 32; o; o >>= 1) {
            a0 += __shfl_down(a0, o);
            a1 += __shfl_down(a1, o);
            a2 += __shfl_down(a2, o);
            a3 += __shfl_down(a3, o);
        }
        if (l == 0 && node < N) {
            float* outp = (tt < 64) ? (g + (size_t)node * OUTC)
                                    : (s + (size_t)node * OUTC);
            outp[0] = a0; outp[1] = a1; outp[2] = a2; outp[3] = a3;
        }
        __syncthreads();   // protect xs/ms/hs before next iteration
    }
}

// ---- kernel 5: gather-mean(g) + self + bias + log_softmax (R4 verbatim) ---
__global__ void final_kernel(const float* __restrict__ g,
                             const int* __restrict__ adj,
                             const int* __restrict__ start,
                             const int* __restrict__ deg,
                             const float* __restrict__ s,
                             const float* __restrict__ b2,
                             float* __restrict__ out) {
    int i = blockIdx.x * blockDim.x + threadIdx.x;
    if (i >= N) return;
    int d  = deg[i];
    int st = start[i];
    float4 acc = make_float4(0.f, 0.f, 0.f, 0.f);
    for (int j = 0; j < d; ++j) {
        int sn = adj[st + j];
        float4 gv = *(const float4*)(g + (size_t)sn * OUTC);
        acc.x += gv.x; acc.y += gv.y; acc.z += gv.z; acc.w += gv.w;
    }
    float inv = 1.0f / fmaxf((float)d, 1.0f);
    float o[OUTC];
    o[0] = acc.x * inv + s[(size_t)i * OUTC + 0] + b2[0];
    o[1] = acc.y * inv + s[(size_t)i * OUTC + 1] + b2[1];
    o[2] = acc.z * inv + s[(size_t)i * OUTC + 2] + b2[2];
    o[3] = acc.w * inv + s[(size_t)i * OUTC + 3] + b2[3];
    float m = fmaxf(fmaxf(o[0], o[1]), fmaxf(o[2], o[3]));
    float sum = 0.f;
#pragma unroll
    for (int k = 0; k < OUTC; ++k)
        sum += expf(o[k] - m);
    float lse = logf(sum);
    float4 ov = make_float4(o[0] - m - lse, o[1] - m - lse,
                            o[2] - m - lse, o[3] - m - lse);
    *(float4*)(out + (size_t)i * OUTC) = ov;
}

extern "C" void kernel_launch(void* const* d_in, const int* in_sizes, int n_in,
                              void* d_out, int out_size, void* d_ws, size_t ws_size,
                              hipStream_t stream) {
    const float* x   = (const float*)d_in[0];
    const int*   ei  = (const int*)d_in[1];
    const float* w1l = (const float*)d_in[2];
    const float* w1r = (const float*)d_in[3];
    const float* b1  = (const float*)d_in[4];
    const float* w2l = (const float*)d_in[5];
    const float* w2r = (const float*)d_in[6];
    const float* b2  = (const float*)d_in[7];
    float* out = (float*)d_out;

    // workspace layout (4B units):
    // [flag 64][deg N][start N][bsum 512][adj E][rank E | (g 4N)(s 4N)][mean1 19N]
    int*   ws    = (int*)d_ws;
    int*   flag  = ws;
    int*   deg   = ws + 64;
    int*   start = deg + N;
    int*   bsum  = start + N;
    int*   adj   = bsum + 512;
    int*   rank  = adj + E;
    float* g     = (float*)rank;          // rank dead after scatter; reuse
    float* s     = g + (size_t)N * OUTC;
    float* mean1 = (float*)(rank + E);

    hipMemsetAsync(deg, 0, (size_t)N * sizeof(int), stream);

    detect_idx64<<<1, 256, 0, stream>>>(ei, flag);
    deg_rank_kernel<<<(E + 255) / 256, 256, 0, stream>>>(ei, deg, rank, flag);
    scan_block<<<NB, 256, 0, stream>>>(deg, start, bsum);
    scan_bsum<<<1, 512, 0, stream>>>(bsum);
    scan_addback<<<NB, 256, 0, stream>>>(start, bsum);
    scatter_kernel<<<(E + 255) / 256, 256, 0, stream>>>(ei, start, rank, adj, flag);
    gather_mean_kernel<<<(N * 32 + 255) / 256, 256, 0, stream>>>(x, adj, start, deg, mean1);
    dense_kernel<<<1792, 256, 0, stream>>>(x, mean1, w1l, w1r, b1, w2l, w2r, g, s);
    final_kernel<<<(N + 255) / 256, 256, 0, stream>>>(g, adj, start, deg, s, b2, out);
}

// Round 7
// 235.092 us; speedup vs baseline: 1.2883x; 1.2883x over previous
//
#include <hip/hip_runtime.h>
#include <math.h>

// GraphSAGE 2-layer, mean aggregation, fp32.
// Round 7: single change vs R6 (passed, 302us): dense_kernel rewritten as
// thread-per-node. R6's dense was barrier-bound (129us, VALUBusy 20%,
// occupancy 54%: 2 nodes per block-iteration x 3 barriers). New structure:
// weights staged to LDS once per block (w1 19x128 x2, w2 128x8, b1: 24KB),
// then each thread privately computes its node: ms/xs in registers,
// every LDS read is wave-uniform (pure broadcast, conflict-free by
// construction), h_o consumed immediately into 8 register accumulators.
// No barriers after staging, no shuffles anywhere (R3/R5 bisect banned the
// wave-shfl family). Dense FLOPs ~1.2 GFLOP => ~10us expected.
// CSR build / gather_mean / final_kernel: R6 verbatim (passing).

constexpr int N    = 100000;
constexpr int E    = 1600000;
constexpr int INC  = 19;
constexpr int HID  = 128;
constexpr int OUTC = 4;
constexpr int NB   = (N + 255) / 256;   // 391 scan blocks

// ---- kernel 0: detect whether edge_index arrived as int64 or int32 -------
__global__ void detect_idx64(const int* __restrict__ ei, int* __restrict__ flag) {
    __shared__ int any;
    if (threadIdx.x == 0) any = 0;
    __syncthreads();
    int v = 0;
    for (int k = threadIdx.x; k < 1024; k += blockDim.x)
        v |= ei[2 * k + 1];
    if (v) atomicOr(&any, 1);
    __syncthreads();
    if (threadIdx.x == 0) *flag = (any == 0) ? 1 : 0;
}

__device__ inline void load_edge(const int* __restrict__ ei, int e, int is64,
                                 int& src, int& dst) {
    if (is64) {
        src = ei[2 * e];
        dst = ei[2 * E + 2 * e];
    } else {
        src = ei[e];
        dst = ei[E + e];
    }
}

// ---- kernel 1: degree histogram + per-edge rank ---------------------------
__global__ void deg_rank_kernel(const int* __restrict__ ei, int* __restrict__ deg,
                                int* __restrict__ rank, const int* __restrict__ flag) {
    int e = blockIdx.x * blockDim.x + threadIdx.x;
    if (e >= E) return;
    int is64 = *flag;
    int dst = is64 ? ei[2 * E + 2 * e] : ei[E + e];
    rank[e] = atomicAdd(&deg[dst], 1);
}

// ---- kernels 2a/2b/2c: exclusive scan of deg -> start ----------------------
__global__ void scan_block(const int* __restrict__ deg, int* __restrict__ start,
                           int* __restrict__ bsum) {
    __shared__ int sd[256];
    int t = threadIdx.x;
    int i = blockIdx.x * 256 + t;
    int v = (i < N) ? deg[i] : 0;
    sd[t] = v;
    __syncthreads();
    for (int off = 1; off < 256; off <<= 1) {
        int add = (t >= off) ? sd[t - off] : 0;
        __syncthreads();
        sd[t] += add;
        __syncthreads();
    }
    if (i < N) start[i] = sd[t] - v;
    if (t == 255) bsum[blockIdx.x] = sd[255];
}

__global__ void scan_bsum(int* __restrict__ bsum) {
    __shared__ int sd[512];
    int t = threadIdx.x;
    int v = (t < NB) ? bsum[t] : 0;
    sd[t] = v;
    __syncthreads();
    for (int off = 1; off < 512; off <<= 1) {
        int add = (t >= off) ? sd[t - off] : 0;
        __syncthreads();
        sd[t] += add;
        __syncthreads();
    }
    if (t < NB) bsum[t] = sd[t] - v;
}

__global__ void scan_addback(int* __restrict__ start, const int* __restrict__ bsum) {
    int i = blockIdx.x * 256 + threadIdx.x;
    if (i < N) start[i] += bsum[blockIdx.x];
}

// ---- kernel 3: atomic-free scatter into CSR -------------------------------
__global__ void scatter_kernel(const int* __restrict__ ei, const int* __restrict__ start,
                               const int* __restrict__ rank, int* __restrict__ adj,
                               const int* __restrict__ flag) {
    int e = blockIdx.x * blockDim.x + threadIdx.x;
    if (e >= E) return;
    int is64 = *flag;
    int src, dst;
    load_edge(ei, e, is64, src, dst);
    adj[start[dst] + rank[e]] = src;
}

// ---- kernel 4a: gather-mean, 32 lanes per node, one channel per lane ------
// (R6 verbatim) No shuffles, no barriers: lane privately sums its channel.
__global__ void gather_mean_kernel(const float* __restrict__ x,
                                   const int* __restrict__ adj,
                                   const int* __restrict__ start,
                                   const int* __restrict__ deg,
                                   float* __restrict__ mean1) {
    int tid  = blockIdx.x * blockDim.x + threadIdx.x;
    int node = tid >> 5;
    int ln   = tid & 31;
    if (node >= N || ln >= INC) return;
    int d  = deg[node];
    int st = start[node];
    float a0 = 0.f, a1 = 0.f;
    int j = 0;
    for (; j + 1 < d; j += 2) {
        int s0 = adj[st + j];
        int s1 = adj[st + j + 1];
        a0 += x[(size_t)s0 * INC + ln];
        a1 += x[(size_t)s1 * INC + ln];
    }
    if (j < d) a0 += x[(size_t)adj[st + j] * INC + ln];
    float inv = 1.0f / fmaxf((float)d, 1.0f);
    mean1[(size_t)node * INC + ln] = (a0 + a1) * inv;
}

// ---- kernel 4b: dense layer1 + layer2 projection, thread-per-node ---------
// All weights in LDS; every compute-phase LDS read is wave-uniform
// (broadcast). ms/xs/accumulators in registers, statically indexed.
__global__ __launch_bounds__(256) void dense_v2(
        const float* __restrict__ x,
        const float* __restrict__ mean1,
        const float* __restrict__ w1l,
        const float* __restrict__ w1r,
        const float* __restrict__ b1,
        const float* __restrict__ w2l,
        const float* __restrict__ w2r,
        float* __restrict__ g,
        float* __restrict__ s) {
    __shared__ float W1L[INC * HID];   // [c][o], natural layout
    __shared__ float W1R[INC * HID];
    __shared__ float W2[HID * 8];      // [o][0..3]=w2l row, [o][4..7]=w2r row
    __shared__ float B1[HID];

    int t = threadIdx.x;
    for (int k = t; k < INC * HID; k += 256) {
        W1L[k] = w1l[k];
        W1R[k] = w1r[k];
    }
    for (int k = t; k < HID * OUTC; k += 256) {
        int o = k >> 2, kk = k & 3;
        W2[o * 8 + kk]     = w2l[k];
        W2[o * 8 + 4 + kk] = w2r[k];
    }
    if (t < HID) B1[t] = b1[t];
    __syncthreads();   // the only barrier

    int node = blockIdx.x * 256 + t;
    if (node >= N) return;

    // per-node inputs -> registers (statically indexed)
    float ms[INC], xs[INC];
#pragma unroll
    for (int c = 0; c < INC; ++c) {
        ms[c] = mean1[(size_t)node * INC + c];
        xs[c] = x[(size_t)node * INC + c];
    }

    float r[8] = {0.f, 0.f, 0.f, 0.f, 0.f, 0.f, 0.f, 0.f};
#pragma unroll 4
    for (int o = 0; o < HID; ++o) {
        float acc = B1[o];
#pragma unroll
        for (int c = 0; c < INC; ++c)
            acc += ms[c] * W1L[c * HID + o] + xs[c] * W1R[c * HID + o];
        float h = fmaxf(acc, 0.0f);
#pragma unroll
        for (int k = 0; k < 8; ++k)
            r[k] += h * W2[o * 8 + k];
    }

    *(float4*)(g + (size_t)node * OUTC) = make_float4(r[0], r[1], r[2], r[3]);
    *(float4*)(s + (size_t)node * OUTC) = make_float4(r[4], r[5], r[6], r[7]);
}

// ---- kernel 5: gather-mean(g) + self + bias + log_softmax (R6 verbatim) ---
__global__ void final_kernel(const float* __restrict__ g,
                             const int* __restrict__ adj,
                             const int* __restrict__ start,
                             const int* __restrict__ deg,
                             const float* __restrict__ s,
                             const float* __restrict__ b2,
                             float* __restrict__ out) {
    int i = blockIdx.x * blockDim.x + threadIdx.x;
    if (i >= N) return;
    int d  = deg[i];
    int st = start[i];
    float4 acc = make_float4(0.f, 0.f, 0.f, 0.f);
    for (int j = 0; j < d; ++j) {
        int sn = adj[st + j];
        float4 gv = *(const float4*)(g + (size_t)sn * OUTC);
        acc.x += gv.x; acc.y += gv.y; acc.z += gv.z; acc.w += gv.w;
    }
    float inv = 1.0f / fmaxf((float)d, 1.0f);
    float o[OUTC];
    o[0] = acc.x * inv + s[(size_t)i * OUTC + 0] + b2[0];
    o[1] = acc.y * inv + s[(size_t)i * OUTC + 1] + b2[1];
    o[2] = acc.z * inv + s[(size_t)i * OUTC + 2] + b2[2];
    o[3] = acc.w * inv + s[(size_t)i * OUTC + 3] + b2[3];
    float m = fmaxf(fmaxf(o[0], o[1]), fmaxf(o[2], o[3]));
    float sum = 0.f;
#pragma unroll
    for (int k = 0; k < OUTC; ++k)
        sum += expf(o[k] - m);
    float lse = logf(sum);
    float4 ov = make_float4(o[0] - m - lse, o[1] - m - lse,
                            o[2] - m - lse, o[3] - m - lse);
    *(float4*)(out + (size_t)i * OUTC) = ov;
}

extern "C" void kernel_launch(void* const* d_in, const int* in_sizes, int n_in,
                              void* d_out, int out_size, void* d_ws, size_t ws_size,
                              hipStream_t stream) {
    const float* x   = (const float*)d_in[0];
    const int*   ei  = (const int*)d_in[1];
    const float* w1l = (const float*)d_in[2];
    const float* w1r = (const float*)d_in[3];
    const float* b1  = (const float*)d_in[4];
    const float* w2l = (const float*)d_in[5];
    const float* w2r = (const float*)d_in[6];
    const float* b2  = (const float*)d_in[7];
    float* out = (float*)d_out;

    // workspace layout (4B units):
    // [flag 64][deg N][start N][bsum 512][adj E][rank E | (g 4N)(s 4N)][mean1 19N]
    int*   ws    = (int*)d_ws;
    int*   flag  = ws;
    int*   deg   = ws + 64;
    int*   start = deg + N;
    int*   bsum  = start + N;
    int*   adj   = bsum + 512;
    int*   rank  = adj + E;
    float* g     = (float*)rank;          // rank dead after scatter; reuse
    float* s     = g + (size_t)N * OUTC;
    float* mean1 = (float*)(rank + E);

    hipMemsetAsync(deg, 0, (size_t)N * sizeof(int), stream);

    detect_idx64<<<1, 256, 0, stream>>>(ei, flag);
    deg_rank_kernel<<<(E + 255) / 256, 256, 0, stream>>>(ei, deg, rank, flag);
    scan_block<<<NB, 256, 0, stream>>>(deg, start, bsum);
    scan_bsum<<<1, 512, 0, stream>>>(bsum);
    scan_addback<<<NB, 256, 0, stream>>>(start, bsum);
    scatter_kernel<<<(E + 255) / 256, 256, 0, stream>>>(ei, start, rank, adj, flag);
    gather_mean_kernel<<<(N * 32 + 255) / 256, 256, 0, stream>>>(x, adj, start, deg, mean1);
    dense_v2<<<NB, 256, 0, stream>>>(x, mean1, w1l, w1r, b1, w2l, w2r, g, s);
    final_kernel<<<(N + 255) / 256, 256, 0, stream>>>(g, adj, start, deg, s, b2, out);
}